// Round 10
// baseline (254.910 us; speedup 1.0000x reference)
//
#include <hip/hip_runtime.h>
#include <hip/hip_bf16.h>
#include <math.h>

#define NB 16
#define ND 256
#define NL 200
#define NT 1000

typedef unsigned short ushort_t;
typedef __bf16 bf16x8 __attribute__((ext_vector_type(8)));
typedef float f32x4 __attribute__((ext_vector_type(4)));

#define LDS_AS(p) ((__attribute__((address_space(3))) void*)(p))
#define GLB_AS(p) ((const __attribute__((address_space(1))) void*)(p))

// ---- workspace layout (float offsets) ----
#define OFF_PHT   0u         // phT[b][l][d] fp32            819200
#define OFF_SK    4966400u   // exclusive cumsum             3200
#define OFF_EW    4969600u   // E[oc][k][d]                  6144
#define OFF_EC    4975744u   //                              6144
#define OFF_BW2   4981888u   //                              24
#define OFF_BC2   4981912u   //                              24
#define OFF_FL    4981936u   // frame_lengths int            16
#define OFF_GT    11535552u  // Gt bf16 [b][256][800]        1638400 floats
#define OFF_WHC   13173952u  // whc bf16 [16000][256]        2048000 floats
#define OFF_WOT   15221952u  // WoT bf16 [512][256]          65536 floats
#define OFF_BASE  15287488u  // base[b][256][8] fp32         32768 floats
#define OFF_PHTB  15320256u  // phTb bf16 [b][256pad][256]   524288 floats
#define OFF_LWT   15844544u  // LwT bf16 [4][256][256]       131072 floats

__device__ __forceinline__ float silu_f(float x){ return x / (1.f + __expf(-x)); }
__device__ __forceinline__ ushort_t f2bf(float x){
  __hip_bfloat16 h = __float2bfloat16(x);
  return *(ushort_t*)&h;
}

// =========== STAGE 1: prep(16) | setup(1584) | transpose(1024) = 2624 blocks ===
__global__ __launch_bounds__(256) void k_stage1(
    const float* __restrict__ dur, const float* __restrict__ ph,
    const float* __restrict__ Wp_w, const float* __restrict__ C_w, const float* __restrict__ bp_w,
    const float* __restrict__ Wp_c, const float* __restrict__ C_c, const float* __restrict__ bp_c,
    const float* __restrict__ Wo, const float* __restrict__ Lw,
    float* __restrict__ sk_ws, int* __restrict__ fl_ws,
    float* __restrict__ o_fm, float* __restrict__ o_fl,
    float* __restrict__ Ew, float* __restrict__ Ec,
    float* __restrict__ bw2, float* __restrict__ bc2,
    ushort_t* __restrict__ WoT, ushort_t* __restrict__ LwT,
    float* __restrict__ phT, ushort_t* __restrict__ phTb)
{
  int bid = blockIdx.x, tid = threadIdx.x;
  if (bid < 16){
    // ---- prep: cumsum, frame_lengths, frame_mask ----
    int b = bid;
    __shared__ float sdur[NL];
    __shared__ float ssk[NL];
    __shared__ int sfl;
    if (tid < NL) sdur[tid] = dur[b*NL + tid];
    __syncthreads();
    if (tid == 0){
      float run = 0.f;
      for (int l = 0; l < NL; ++l){ ssk[l] = run; run += sdur[l]; }
      int fl = (int)rintf(run);          // round-half-even, matches jnp.round
      fl = fl < 0 ? 0 : (fl > NT ? NT : fl);
      sfl = fl; fl_ws[b] = fl; o_fl[b] = (float)fl;
    }
    __syncthreads();
    if (tid < NL) sk_ws[b*NL + tid] = ssk[tid];
    for (int t = tid; t < NT; t += 256) o_fm[b*NT + t] = (t < sfl) ? 1.f : 0.f;
  } else if (bid < 1600){
    // ---- setup: conv-fold E/bias2 + WoT/LwT bf16 packs ----
    int sbid = bid - 16;
    if (sbid < 48){
      int gid = sbid*256 + tid;          // 12288 = 2 * 8*3*256
      int branch = gid / 6144;
      int r = gid % 6144;
      int d = r & 255;
      int ock = r >> 8;                  // oc*3+k
      int oc = ock / 3, k = ock % 3;
      const float* Wp = branch ? Wp_c : Wp_w;
      const float* C  = branch ? C_c  : C_w;
      float acc = 0.f;
      for (int i = 0; i < ND; ++i) acc += C[(oc*ND + i)*3 + k] * Wp[i*ND + d];
      (branch ? Ec : Ew)[r] = acc;
      if (d == 0){
        const float* bp = branch ? bp_c : bp_w;
        float bb = 0.f;
        for (int i = 0; i < ND; ++i) bb += C[(oc*ND + i)*3 + k] * bp[i];
        (branch ? bc2 : bw2)[ock] = bb;
      }
    } else {
      int gid = (sbid - 48)*256 + tid;   // 393216
      if (gid < 131072){
        int n = gid >> 8, k = gid & 255;
        WoT[gid] = f2bf(Wo[(size_t)k*512 + n]);
      } else {
        int r = gid - 131072;            // q*65536 + n*256 + d
        int d = r & 255;
        int qn = r >> 8;
        int q = qn >> 8, n = qn & 255;
        LwT[r] = f2bf(Lw[((size_t)q*256 + d)*256 + n]);
      }
    }
  } else {
    // ---- transpose: ph (b,d,l) -> phT fp32 + phTb bf16 (l padded to 256) ----
    int r = bid - 1600;                  // 1024 = 8 x 8 x 16
    int xb = r & 7, yb = (r >> 3) & 7, b = r >> 6;
    int l0 = xb*32, d0 = yb*32;
    int tx = tid & 31, ty = tid >> 5;    // 32 x 8
    __shared__ float tile[32][33];
    #pragma unroll
    for (int i = 0; i < 4; ++i){
      int d = d0 + ty + i*8, l = l0 + tx;
      tile[ty + i*8][tx] = (l < NL) ? ph[((size_t)b*ND + d)*NL + l] : 0.f;
    }
    __syncthreads();
    #pragma unroll
    for (int i = 0; i < 4; ++i){
      int l = l0 + ty + i*8, d = d0 + tx;
      float v = tile[tx][ty + i*8];
      if (l < NL) phT[((size_t)b*NL + l)*ND + d] = v;
      phTb[((size_t)b*256 + l)*ND + d] = f2bf(v);   // rows >=200 zero
    }
  }
}

// =========== STAGE 2: hwc2+base(256) | gemmG(256) = 512 blocks =================
// BUGFIX R10: gemmG needs 2x2x(NB*4) = 256 blocks; R7-R9 launched only 64,
// leaving Gt[b] for b>=4 as 0xAA poison (the absmax 1.717651 regression).
__global__ __launch_bounds__(256) void k_stage2(
    const float* __restrict__ phT,
    const float* __restrict__ dur, const float* __restrict__ sk_ws,
    const float* __restrict__ Ew, const float* __restrict__ Ec,
    const float* __restrict__ bw2, const float* __restrict__ bc2,
    const float* __restrict__ cbw, const float* __restrict__ cbc,
    const float* __restrict__ Mw, const float* __restrict__ mbw,
    const float* __restrict__ Mc, const float* __restrict__ mbc,
    float4* __restrict__ base,
    const ushort_t* __restrict__ LwT, const ushort_t* __restrict__ phTb,
    ushort_t* __restrict__ Gt)
{
  int bid = blockIdx.x, tid = threadIdx.x;
  if (bid < 256){
    // ---- fused conv-swish h + t-invariant MLP bases per (b,l) ----
    int b = bid >> 4, x = bid & 15;
    if (x >= 13){
      int l0 = 208 + (x - 13)*16;
      if (tid < 32)
        base[((size_t)(b*256 + l0 + (tid >> 1)))*2 + (tid & 1)] = make_float4(0,0,0,0);
      return;
    }
    __shared__ float sh[16][17];
    int lu = tid >> 4, u = tid & 15;
    int l = x*16 + lu;
    float h = 0.f;
    if (l < NL){
      int branch = u >> 3, oc = u & 7;
      const float* E  = branch ? Ec  : Ew;
      const float* b2 = branch ? bc2 : bw2;
      float val = (branch ? cbc : cbw)[oc];
      #pragma unroll
      for (int k = 0; k < 3; ++k){
        int ll = l + k - 1;
        if (ll < 0 || ll >= NL) continue;  // SAME zero-pad: drop term+bias
        float acc = b2[oc*3 + k];
        const float4* Er = (const float4*)(E + (oc*3 + k)*ND);
        const float4* pr = (const float4*)(phT + ((size_t)b*NL + ll)*ND);
        #pragma unroll 8
        for (int d = 0; d < 64; ++d){
          float4 e = Er[d], p = pr[d];
          acc += e.x*p.x + e.y*p.y + e.z*p.z + e.w*p.w;
        }
        val += acc;
      }
      float pm = (dur[b*NL + l] > 0.5f) ? 1.f : 0.f;
      h = silu_f(val) * pm;
    }
    sh[lu][u] = h;
    __syncthreads();
    if (tid < 16){
      int ll = x*16 + tid;
      float4 o0 = make_float4(0,0,0,0);
      float4 o1 = make_float4(0,0,0,0);
      if (ll < NL){
        float dl  = dur[b*NL + ll];
        float pm  = (dl > 0.5f) ? 1.f : 0.f;
        float skl = sk_ws[b*NL + ll];
        float c1[4], c2[2];
        #pragma unroll
        for (int q = 0; q < 4; ++q) c1[q] = mbw[q] + dl*Mw[4 + q] - skl*Mw[q];
        #pragma unroll
        for (int p = 0; p < 2; ++p) c2[p] = mbc[p] + dl*Mc[2 + p] - skl*Mc[p];
        #pragma unroll
        for (int j = 0; j < 8; ++j){
          float hwv = sh[tid][j], hcv = sh[tid][8 + j];
          #pragma unroll
          for (int q = 0; q < 4; ++q) c1[q] += hwv*Mw[(2 + j)*4 + q];
          #pragma unroll
          for (int p = 0; p < 2; ++p) c2[p] += hcv*Mc[(2 + j)*2 + p];
        }
        o0 = make_float4(c1[0], c1[1], c1[2], c1[3]);
        o1 = make_float4(c2[0], c2[1], pm, 0.f);
      }
      base[((size_t)(b*256 + ll))*2 + 0] = o0;
      base[((size_t)(b*256 + ll))*2 + 1] = o1;
    }
  } else {
    // ---- MFMA Gt[b][n][q*200+l] = sum_d LwT[q][n][d] * phTb[b][l][d] ----
    int r = bid - 256;                   // 256 = 2 x 2 x 64  (bq in [0,64))
    int xb = r & 1, yb = (r >> 1) & 1, bq = r >> 2;
    int b = bq >> 2, q = bq & 3;
    int m0 = yb * 128;                   // n dim
    int n0 = xb * 128;                   // l dim (padded)
    __shared__ ushort_t As[4096];
    __shared__ ushort_t Bs[4096];
    int lane = tid & 63, wave = tid >> 6;
    int wm = wave >> 1, wn = wave & 1;
    int col = lane & 15, kg4 = lane >> 4;
    f32x4 acc[4][4] = {};
    for (int kt = 0; kt < 8; ++kt){
      int k0 = kt*32;
      #pragma unroll
      for (int rr = 0; rr < 2; ++rr){
        int o = wave*1024 + rr*4096;
        int co = o + (lane << 4);
        int kg = co >> 11, row = (co >> 4) & 127;
        const ushort_t* ga = LwT + ((size_t)(q*256 + m0 + row))*256 + k0 + kg*8;
        __builtin_amdgcn_global_load_lds(GLB_AS(ga), LDS_AS(As + (o >> 1)), 16, 0, 0);
        const ushort_t* gb = phTb + ((size_t)(b*256 + n0 + row))*256 + k0 + kg*8;
        __builtin_amdgcn_global_load_lds(GLB_AS(gb), LDS_AS(Bs + (o >> 1)), 16, 0, 0);
      }
      __builtin_amdgcn_s_waitcnt(0);
      __syncthreads();
      const bf16x8* Av = (const bf16x8*)As;
      const bf16x8* Bv = (const bf16x8*)Bs;
      bf16x8 afr[4], bfr[4];
      #pragma unroll
      for (int i = 0; i < 4; ++i) afr[i] = Av[kg4*128 + wm*64 + i*16 + col];
      #pragma unroll
      for (int j = 0; j < 4; ++j) bfr[j] = Bv[kg4*128 + wn*64 + j*16 + col];
      #pragma unroll
      for (int i = 0; i < 4; ++i)
        #pragma unroll
        for (int j = 0; j < 4; ++j)
          acc[i][j] = __builtin_amdgcn_mfma_f32_16x16x32_bf16(afr[i], bfr[j], acc[i][j], 0, 0, 0);
      __syncthreads();
    }
    int rq = lane >> 4;
    #pragma unroll
    for (int i = 0; i < 4; ++i){
      #pragma unroll
      for (int rr = 0; rr < 4; ++rr){
        int n = m0 + wm*64 + i*16 + rq*4 + rr;
        #pragma unroll
        for (int j = 0; j < 4; ++j){
          int l = n0 + wn*64 + j*16 + col;
          if (l < NL)
            Gt[((size_t)b*ND + n)*800 + q*NL + l] = f2bf(acc[i][j][rr]);
        }
      }
    }
  }
}

// =========== K3: FUSED softmax + V-GEMM per (b, 32-t tile) =====================
#define AP 808
__global__ __launch_bounds__(256) void k_wv_fused(
    const float4* __restrict__ base,
    const int* __restrict__ fl_ws,
    const float* __restrict__ Mw, const float* __restrict__ Mc,
    const ushort_t* __restrict__ Gt,    // [16][256][800] bf16
    const float* __restrict__ Lc,       // [8][256]
    const float* __restrict__ lbc,      // [256]
    const float* __restrict__ lbw,      // [256]
    float* __restrict__ wout,
    ushort_t* __restrict__ whc)         // [16000][256] bf16
{
  __shared__ ushort_t As[32*AP];   // 50.5 KB w-tile [t_local][k=q*200+l]
  __shared__ ushort_t Bs[8192];    // 16 KB  [kg(4)][n(256)][8]
  __shared__ float    wcs[32][8];  // 1 KB per-t wc
  int b = blockIdx.y;
  int m0 = blockIdx.x * 32;        // t tile (32 tiles cover 0..1023)
  int tid = threadIdx.x, lane = tid & 63, wave = tid >> 6;
  int col = lane & 15, kg4 = lane >> 4;
  int fl = fl_ws[b];

  // ---------------- phase 1: softmax for 8 t's per wave ----------------
  for (int s = 0; s < 8; ++s){
    int tl = wave*8 + s;
    int t = m0 + tl;
    if (t >= fl){                       // masked or beyond NT
      for (int k = lane; k < 800; k += 64) As[tl*AP + k] = 0;
      if (lane < 8) wcs[tl][lane] = 0.f;
      if (t < NT){
        #pragma unroll
        for (int q = 0; q < 4; ++q)
          #pragma unroll
          for (int c = 0; c < 4; ++c){
            int l = c*64 + lane;
            if (l < NL) wout[(((size_t)(b*4 + q))*NT + t)*NL + l] = 0.f;
          }
      }
      continue;
    }
    float t1 = (float)(t + 1);
    float tqw[4], tqc[2];
    #pragma unroll
    for (int q = 0; q < 4; ++q) tqw[q] = t1 * Mw[q];
    #pragma unroll
    for (int p = 0; p < 2; ++p) tqc[p] = t1 * Mc[p];
    float z[4][4], cv[4][2], msk[4];
    float m[4] = {-INFINITY, -INFINITY, -INFINITY, -INFINITY};
    #pragma unroll
    for (int c = 0; c < 4; ++c){
      int l = c*64 + lane;
      float4 b0 = base[((size_t)(b*256 + l))*2 + 0];
      float4 b1 = base[((size_t)(b*256 + l))*2 + 1];
      float pm = b1.z;
      msk[c] = pm;
      float zz[4] = { b0.x + tqw[0], b0.y + tqw[1], b0.z + tqw[2], b0.w + tqw[3] };
      #pragma unroll
      for (int q = 0; q < 4; ++q){
        float sv = silu_f(zz[q]);
        z[c][q] = (pm > 0.f) ? sv : -INFINITY;
        m[q] = fmaxf(m[q], z[c][q]);
      }
      cv[c][0] = silu_f(b1.x + tqc[0]);
      cv[c][1] = silu_f(b1.y + tqc[1]);
    }
    #pragma unroll
    for (int q = 0; q < 4; ++q){
      float v = m[q];
      #pragma unroll
      for (int off = 32; off; off >>= 1) v = fmaxf(v, __shfl_xor(v, off));
      m[q] = v;
    }
    float s4[4] = {0,0,0,0};
    #pragma unroll
    for (int c = 0; c < 4; ++c){
      #pragma unroll
      for (int q = 0; q < 4; ++q){
        float e = (msk[c] > 0.f) ? __expf(z[c][q] - m[q]) : 0.f;
        z[c][q] = e;
        s4[q] += e;
      }
    }
    #pragma unroll
    for (int q = 0; q < 4; ++q){
      float v = s4[q];
      #pragma unroll
      for (int off = 32; off; off >>= 1) v += __shfl_xor(v, off);
      s4[q] = 1.f / v;
    }
    float wc[8] = {0,0,0,0,0,0,0,0};
    #pragma unroll
    for (int c = 0; c < 4; ++c){
      int l = c*64 + lane;
      bool lv = l < NL;
      #pragma unroll
      for (int q = 0; q < 4; ++q){
        float wq = z[c][q] * s4[q];
        if (lv){
          wout[(((size_t)(b*4 + q))*NT + t)*NL + l] = wq;
          As[tl*AP + q*NL + l] = f2bf(wq);
        }
        wc[q*2 + 0] += wq * cv[c][0];
        wc[q*2 + 1] += wq * cv[c][1];
      }
    }
    #pragma unroll
    for (int u = 0; u < 8; ++u){
      float v = wc[u];
      #pragma unroll
      for (int off = 32; off; off >>= 1) v += __shfl_xor(v, off);
      wc[u] = v;
    }
    if (lane == 0){
      #pragma unroll
      for (int u = 0; u < 8; ++u) wcs[tl][u] = wc[u];
    }
  }
  __syncthreads();

  // ---------------- phase 2: MFMA over K=800 ----------------
  f32x4 acc[2][4] = {};
  for (int kt = 0; kt < 25; ++kt){
    int k0 = kt*32;
    #pragma unroll
    for (int r = 0; r < 4; ++r){
      int o = (wave*4 + r) << 10;          // 16 x 1KB chunks = 16 KB
      int co = o + (lane << 4);
      int kg = co >> 12, row = (co >> 4) & 255;
      const ushort_t* gb = Gt + ((size_t)(b*ND + row))*800 + k0 + kg*8;
      __builtin_amdgcn_global_load_lds(GLB_AS(gb), LDS_AS(Bs + (co >> 1)), 16, 0, 0);
    }
    __builtin_amdgcn_s_waitcnt(0);
    __syncthreads();
    const bf16x8* Bv = (const bf16x8*)Bs;
    bf16x8 afr[2], bfr[4];
    #pragma unroll
    for (int i = 0; i < 2; ++i)
      afr[i] = *(const bf16x8*)(&As[(i*16 + col)*AP + k0 + kg4*8]);
    #pragma unroll
    for (int j = 0; j < 4; ++j) bfr[j] = Bv[kg4*256 + wave*64 + j*16 + col];
    #pragma unroll
    for (int i = 0; i < 2; ++i)
      #pragma unroll
      for (int j = 0; j < 4; ++j)
        acc[i][j] = __builtin_amdgcn_mfma_f32_16x16x32_bf16(afr[i], bfr[j], acc[i][j], 0, 0, 0);
    __syncthreads();
  }

  // ---- epilogue: whc[t][n] = fm*(vh + lbw + (lbc + wc.Lc)) -> global ----
  int rq = lane >> 4;
  float lcn[4][8], lbn[4], lbwn[4];
  #pragma unroll
  for (int j = 0; j < 4; ++j){
    int n = wave*64 + j*16 + col;
    lbn[j] = lbc[n]; lbwn[j] = lbw[n];
    #pragma unroll
    for (int u = 0; u < 8; ++u) lcn[j][u] = Lc[u*ND + n];
  }
  #pragma unroll
  for (int i = 0; i < 2; ++i){
    #pragma unroll
    for (int r = 0; r < 4; ++r){
      int tl = i*16 + rq*4 + r;
      int t = m0 + tl;
      if (t >= NT) continue;
      float f = (t < fl) ? 1.f : 0.f;
      #pragma unroll
      for (int j = 0; j < 4; ++j){
        float vcv = lbn[j]
          + wcs[tl][0]*lcn[j][0] + wcs[tl][1]*lcn[j][1]
          + wcs[tl][2]*lcn[j][2] + wcs[tl][3]*lcn[j][3]
          + wcs[tl][4]*lcn[j][4] + wcs[tl][5]*lcn[j][5]
          + wcs[tl][6]*lcn[j][6] + wcs[tl][7]*lcn[j][7];
        int n = wave*64 + j*16 + col;
        whc[((size_t)b*NT + t)*ND + n] = f2bf(f * (acc[i][j][r] + lbwn[j] + vcv));
      }
    }
  }
}

// ------- K4: MFMA out = WoT(s-rows) x whc(bt-rows): coalesced t-stores ---------
__global__ __launch_bounds__(256) void k_gemmO_mfma(
    const ushort_t* __restrict__ whc,   // [16000][256] bf16
    const ushort_t* __restrict__ WoT,   // [512][256] bf16
    const float* __restrict__ bo,       // [512]
    float* __restrict__ o_mean, float* __restrict__ o_lstd)
{
  __shared__ ushort_t As[4096];
  __shared__ ushort_t Bs[4096];
  int m0 = blockIdx.y * 128;            // s (4 tiles over 512)
  int n0 = blockIdx.x * 128;            // bt (125 tiles over 16000)
  int tid = threadIdx.x, lane = tid & 63, wave = tid >> 6;
  int wm = wave >> 1, wn = wave & 1;
  int col = lane & 15, kg4 = lane >> 4;

  f32x4 acc[4][4] = {};

  for (int kt = 0; kt < 8; ++kt){
    int k0 = kt*32;
    #pragma unroll
    for (int r = 0; r < 2; ++r){
      int o = wave*1024 + r*4096;
      int co = o + (lane << 4);
      int kg = co >> 11, row = (co >> 4) & 127;
      const ushort_t* ga = WoT + ((size_t)(m0 + row))*ND + k0 + kg*8;
      __builtin_amdgcn_global_load_lds(GLB_AS(ga), LDS_AS(As + (o >> 1)), 16, 0, 0);
      const ushort_t* gb = whc + ((size_t)(n0 + row))*ND + k0 + kg*8;
      __builtin_amdgcn_global_load_lds(GLB_AS(gb), LDS_AS(Bs + (o >> 1)), 16, 0, 0);
    }
    __builtin_amdgcn_s_waitcnt(0);
    __syncthreads();
    const bf16x8* Av = (const bf16x8*)As;
    const bf16x8* Bv = (const bf16x8*)Bs;
    bf16x8 afr[4], bfr[4];
    #pragma unroll
    for (int i = 0; i < 4; ++i) afr[i] = Av[kg4*128 + wm*64 + i*16 + col];
    #pragma unroll
    for (int j = 0; j < 4; ++j) bfr[j] = Bv[kg4*128 + wn*64 + j*16 + col];
    #pragma unroll
    for (int i = 0; i < 4; ++i)
      #pragma unroll
      for (int j = 0; j < 4; ++j)
        acc[i][j] = __builtin_amdgcn_mfma_f32_16x16x32_bf16(afr[i], bfr[j], acc[i][j], 0, 0, 0);
    __syncthreads();
  }

  int rq = lane >> 4;
  #pragma unroll
  for (int i = 0; i < 4; ++i){
    #pragma unroll
    for (int r = 0; r < 4; ++r){
      int s = m0 + wm*64 + i*16 + rq*4 + r;
      float bov = bo[s];
      #pragma unroll
      for (int j = 0; j < 4; ++j){
        int bt = n0 + wn*64 + j*16 + col;
        int b = bt / NT, t = bt - b*NT;
        float v = acc[i][j][r] + bov;
        if (s < ND) o_mean[((size_t)b*ND + s)*NT + t] = v;
        else        o_lstd[((size_t)b*ND + (s - ND))*NT + t] = v;
      }
    }
  }
}

extern "C" void kernel_launch(void* const* d_in, const int* in_sizes, int n_in,
                              void* d_out, int out_size, void* d_ws, size_t ws_size,
                              hipStream_t stream)
{
  const float* dur = (const float*)d_in[0];
  const float* ph  = (const float*)d_in[1];
  // d_in[2] phoneme_mask: unused (pm == durations > 0)
  const float* Wpw = (const float*)d_in[3];
  const float* bpw = (const float*)d_in[4];
  const float* Cw  = (const float*)d_in[5];
  const float* cbw = (const float*)d_in[6];
  const float* Mw  = (const float*)d_in[7];
  const float* mbw = (const float*)d_in[8];
  const float* Lw  = (const float*)d_in[9];
  const float* lbw = (const float*)d_in[10];
  const float* Wpc = (const float*)d_in[11];
  const float* bpc = (const float*)d_in[12];
  const float* Cc  = (const float*)d_in[13];
  const float* cbc = (const float*)d_in[14];
  const float* Mc  = (const float*)d_in[15];
  const float* mbc = (const float*)d_in[16];
  const float* Lc  = (const float*)d_in[17];
  const float* lbc = (const float*)d_in[18];
  const float* Wo  = (const float*)d_in[19];
  const float* bo  = (const float*)d_in[20];

  float* out    = (float*)d_out;
  float* o_mean = out;
  float* o_lstd = out + (size_t)NB*ND*NT;
  float* o_fm   = o_lstd + (size_t)NB*ND*NT;
  float* o_fl   = o_fm + NB*NT;
  float* o_w    = o_fl + NB;

  float* ws   = (float*)d_ws;
  float* phT  = ws + OFF_PHT;
  float* sk   = ws + OFF_SK;
  float* Ew   = ws + OFF_EW;
  float* Ec   = ws + OFF_EC;
  float* bw2  = ws + OFF_BW2;
  float* bc2  = ws + OFF_BC2;
  int*   fl   = (int*)(ws + OFF_FL);
  ushort_t* Gt   = (ushort_t*)(ws + OFF_GT);
  ushort_t* whc  = (ushort_t*)(ws + OFF_WHC);
  ushort_t* WoT  = (ushort_t*)(ws + OFF_WOT);
  float4*   base = (float4*)(ws + OFF_BASE);
  ushort_t* phTb = (ushort_t*)(ws + OFF_PHTB);
  ushort_t* LwT  = (ushort_t*)(ws + OFF_LWT);

  k_stage1<<<2624, 256, 0, stream>>>(dur, ph, Wpw, Cw, bpw, Wpc, Cc, bpc, Wo, Lw,
                                     sk, fl, o_fm, o_fl, Ew, Ec, bw2, bc2,
                                     WoT, LwT, phT, phTb);
  k_stage2<<<512, 256, 0, stream>>>(phT, dur, sk, Ew, Ec, bw2, bc2, cbw, cbc,
                                    Mw, mbw, Mc, mbc, base, LwT, phTb, Gt);
  {
    dim3 g(32, NB);
    k_wv_fused<<<g, 256, 0, stream>>>(base, fl, Mw, Mc, Gt, Lc, lbc, lbw,
                                      o_w, whc);
  }
  {
    dim3 g(125, 4);
    k_gemmO_mfma<<<g, 256, 0, stream>>>(whc, WoT, bo, o_mean, o_lstd);
  }
}

// Round 11
// 250.967 us; speedup vs baseline: 1.0157x; 1.0157x over previous
//
#include <hip/hip_runtime.h>
#include <hip/hip_bf16.h>
#include <math.h>

#define NB 16
#define ND 256
#define NL 200
#define NT 1000

typedef unsigned short ushort_t;
typedef __bf16 bf16x8 __attribute__((ext_vector_type(8)));
typedef float f32x4 __attribute__((ext_vector_type(4)));

#define LDS_AS(p) ((__attribute__((address_space(3))) void*)(p))
#define GLB_AS(p) ((const __attribute__((address_space(1))) void*)(p))

// ---- workspace layout (float offsets) ----
#define OFF_PHT   0u         // phT[b][l][d] fp32            819200
#define OFF_SK    4966400u   // exclusive cumsum             3200
#define OFF_EW    4969600u   // E[oc][k][d]                  6144
#define OFF_EC    4975744u   //                              6144
#define OFF_BW2   4981888u   //                              24
#define OFF_BC2   4981912u   //                              24
#define OFF_FL    4981936u   // frame_lengths int            16
#define OFF_GT    11535552u  // Gt bf16 [b][256][800]        1638400 floats
#define OFF_WHC   13173952u  // whc bf16 [16000][256]        2048000 floats
#define OFF_WOT   15221952u  // WoT bf16 [512][256]          65536 floats
#define OFF_BASE  15287488u  // base[b][256][8] fp32         32768 floats
#define OFF_PHTB  15320256u  // phTb bf16 [b][256pad][256]   524288 floats
#define OFF_LWT   15844544u  // LwT bf16 [4][256][256]       131072 floats

__device__ __forceinline__ float silu_f(float x){ return x / (1.f + __expf(-x)); }
__device__ __forceinline__ ushort_t f2bf(float x){
  __hip_bfloat16 h = __float2bfloat16(x);
  return *(ushort_t*)&h;
}

// =========== STAGE 1: prep(16) | setup(1584) | transpose(1024) = 2624 blocks ===
__global__ __launch_bounds__(256) void k_stage1(
    const float* __restrict__ dur, const float* __restrict__ ph,
    const float* __restrict__ Wp_w, const float* __restrict__ C_w, const float* __restrict__ bp_w,
    const float* __restrict__ Wp_c, const float* __restrict__ C_c, const float* __restrict__ bp_c,
    const float* __restrict__ Wo, const float* __restrict__ Lw,
    float* __restrict__ sk_ws, int* __restrict__ fl_ws,
    float* __restrict__ o_fm, float* __restrict__ o_fl,
    float* __restrict__ Ew, float* __restrict__ Ec,
    float* __restrict__ bw2, float* __restrict__ bc2,
    ushort_t* __restrict__ WoT, ushort_t* __restrict__ LwT,
    float* __restrict__ phT, ushort_t* __restrict__ phTb)
{
  int bid = blockIdx.x, tid = threadIdx.x;
  if (bid < 16){
    // ---- prep: cumsum, frame_lengths, frame_mask ----
    int b = bid;
    __shared__ float sdur[NL];
    __shared__ float ssk[NL];
    __shared__ int sfl;
    if (tid < NL) sdur[tid] = dur[b*NL + tid];
    __syncthreads();
    if (tid == 0){
      float run = 0.f;
      for (int l = 0; l < NL; ++l){ ssk[l] = run; run += sdur[l]; }
      int fl = (int)rintf(run);          // round-half-even, matches jnp.round
      fl = fl < 0 ? 0 : (fl > NT ? NT : fl);
      sfl = fl; fl_ws[b] = fl; o_fl[b] = (float)fl;
    }
    __syncthreads();
    if (tid < NL) sk_ws[b*NL + tid] = ssk[tid];
    for (int t = tid; t < NT; t += 256) o_fm[b*NT + t] = (t < sfl) ? 1.f : 0.f;
  } else if (bid < 1600){
    // ---- setup: conv-fold E/bias2 + WoT/LwT bf16 packs ----
    int sbid = bid - 16;
    if (sbid < 48){
      int gid = sbid*256 + tid;          // 12288 = 2 * 8*3*256
      int branch = gid / 6144;
      int r = gid % 6144;
      int d = r & 255;
      int ock = r >> 8;                  // oc*3+k
      int oc = ock / 3, k = ock % 3;
      const float* Wp = branch ? Wp_c : Wp_w;
      const float* C  = branch ? C_c  : C_w;
      float acc = 0.f;
      for (int i = 0; i < ND; ++i) acc += C[(oc*ND + i)*3 + k] * Wp[i*ND + d];
      (branch ? Ec : Ew)[r] = acc;
      if (d == 0){
        const float* bp = branch ? bp_c : bp_w;
        float bb = 0.f;
        for (int i = 0; i < ND; ++i) bb += C[(oc*ND + i)*3 + k] * bp[i];
        (branch ? bc2 : bw2)[ock] = bb;
      }
    } else {
      int gid = (sbid - 48)*256 + tid;   // 393216
      if (gid < 131072){
        int n = gid >> 8, k = gid & 255;
        WoT[gid] = f2bf(Wo[(size_t)k*512 + n]);
      } else {
        int r = gid - 131072;            // q*65536 + n*256 + d
        int d = r & 255;
        int qn = r >> 8;
        int q = qn >> 8, n = qn & 255;
        LwT[r] = f2bf(Lw[((size_t)q*256 + d)*256 + n]);
      }
    }
  } else {
    // ---- transpose: ph (b,d,l) -> phT fp32 + phTb bf16 (l padded to 256) ----
    int r = bid - 1600;                  // 1024 = 8 x 8 x 16
    int xb = r & 7, yb = (r >> 3) & 7, b = r >> 6;
    int l0 = xb*32, d0 = yb*32;
    int tx = tid & 31, ty = tid >> 5;    // 32 x 8
    __shared__ float tile[32][33];
    #pragma unroll
    for (int i = 0; i < 4; ++i){
      int d = d0 + ty + i*8, l = l0 + tx;
      tile[ty + i*8][tx] = (l < NL) ? ph[((size_t)b*ND + d)*NL + l] : 0.f;
    }
    __syncthreads();
    #pragma unroll
    for (int i = 0; i < 4; ++i){
      int l = l0 + ty + i*8, d = d0 + tx;
      float v = tile[tx][ty + i*8];
      if (l < NL) phT[((size_t)b*NL + l)*ND + d] = v;
      phTb[((size_t)b*256 + l)*ND + d] = f2bf(v);   // rows >=200 zero
    }
  }
}

// =========== STAGE 2: hwc2+base(256) | gemmG(256, direct-load) = 512 blocks ====
__global__ __launch_bounds__(256) void k_stage2(
    const float* __restrict__ phT,
    const float* __restrict__ dur, const float* __restrict__ sk_ws,
    const float* __restrict__ Ew, const float* __restrict__ Ec,
    const float* __restrict__ bw2, const float* __restrict__ bc2,
    const float* __restrict__ cbw, const float* __restrict__ cbc,
    const float* __restrict__ Mw, const float* __restrict__ mbw,
    const float* __restrict__ Mc, const float* __restrict__ mbc,
    float4* __restrict__ base,
    const ushort_t* __restrict__ LwT, const ushort_t* __restrict__ phTb,
    ushort_t* __restrict__ Gt)
{
  int bid = blockIdx.x, tid = threadIdx.x;
  if (bid < 256){
    // ---- fused conv-swish h + t-invariant MLP bases per (b,l) ----
    int b = bid >> 4, x = bid & 15;
    if (x >= 13){
      int l0 = 208 + (x - 13)*16;
      if (tid < 32)
        base[((size_t)(b*256 + l0 + (tid >> 1)))*2 + (tid & 1)] = make_float4(0,0,0,0);
      return;
    }
    __shared__ float sh[16][17];
    int lu = tid >> 4, u = tid & 15;
    int l = x*16 + lu;
    float h = 0.f;
    if (l < NL){
      int branch = u >> 3, oc = u & 7;
      const float* E  = branch ? Ec  : Ew;
      const float* b2 = branch ? bc2 : bw2;
      float val = (branch ? cbc : cbw)[oc];
      #pragma unroll
      for (int k = 0; k < 3; ++k){
        int ll = l + k - 1;
        if (ll < 0 || ll >= NL) continue;  // SAME zero-pad: drop term+bias
        float acc = b2[oc*3 + k];
        const float4* Er = (const float4*)(E + (oc*3 + k)*ND);
        const float4* pr = (const float4*)(phT + ((size_t)b*NL + ll)*ND);
        #pragma unroll 8
        for (int d = 0; d < 64; ++d){
          float4 e = Er[d], p = pr[d];
          acc += e.x*p.x + e.y*p.y + e.z*p.z + e.w*p.w;
        }
        val += acc;
      }
      float pm = (dur[b*NL + l] > 0.5f) ? 1.f : 0.f;
      h = silu_f(val) * pm;
    }
    sh[lu][u] = h;
    __syncthreads();
    if (tid < 16){
      int ll = x*16 + tid;
      float4 o0 = make_float4(0,0,0,0);
      float4 o1 = make_float4(0,0,0,0);
      if (ll < NL){
        float dl  = dur[b*NL + ll];
        float pm  = (dl > 0.5f) ? 1.f : 0.f;
        float skl = sk_ws[b*NL + ll];
        float c1[4], c2[2];
        #pragma unroll
        for (int q = 0; q < 4; ++q) c1[q] = mbw[q] + dl*Mw[4 + q] - skl*Mw[q];
        #pragma unroll
        for (int p = 0; p < 2; ++p) c2[p] = mbc[p] + dl*Mc[2 + p] - skl*Mc[p];
        #pragma unroll
        for (int j = 0; j < 8; ++j){
          float hwv = sh[tid][j], hcv = sh[tid][8 + j];
          #pragma unroll
          for (int q = 0; q < 4; ++q) c1[q] += hwv*Mw[(2 + j)*4 + q];
          #pragma unroll
          for (int p = 0; p < 2; ++p) c2[p] += hcv*Mc[(2 + j)*2 + p];
        }
        o0 = make_float4(c1[0], c1[1], c1[2], c1[3]);
        o1 = make_float4(c2[0], c2[1], pm, 0.f);
      }
      base[((size_t)(b*256 + ll))*2 + 0] = o0;
      base[((size_t)(b*256 + ll))*2 + 1] = o1;
    }
  } else {
    // ---- MFMA Gt = LwT x phTb^T, direct-register loads, barrier-free ----
    int r = bid - 256;                   // 256 = 2 x 2 x 64  (bq in [0,64))
    int xb = r & 1, yb = (r >> 1) & 1, bq = r >> 2;
    int b = bq >> 2, q = bq & 3;
    int m0 = yb * 128;                   // n dim
    int n0 = xb * 128;                   // l dim (padded)
    int lane = tid & 63, wave = tid >> 6;
    int wm = wave >> 1, wn = wave & 1;
    int col = lane & 15, kg4 = lane >> 4;
    f32x4 acc[4][4] = {};
    for (int kt = 0; kt < 8; ++kt){
      int k0 = kt*32;
      bf16x8 afr[4], bfr[4];
      #pragma unroll
      for (int i = 0; i < 4; ++i)
        afr[i] = *(const bf16x8*)(LwT + ((size_t)(q*256 + m0 + wm*64 + i*16 + col))*256 + k0 + kg4*8);
      #pragma unroll
      for (int j = 0; j < 4; ++j)
        bfr[j] = *(const bf16x8*)(phTb + ((size_t)(b*256 + n0 + wn*64 + j*16 + col))*256 + k0 + kg4*8);
      #pragma unroll
      for (int i = 0; i < 4; ++i)
        #pragma unroll
        for (int j = 0; j < 4; ++j)
          acc[i][j] = __builtin_amdgcn_mfma_f32_16x16x32_bf16(afr[i], bfr[j], acc[i][j], 0, 0, 0);
    }
    int rq = lane >> 4;
    #pragma unroll
    for (int i = 0; i < 4; ++i){
      #pragma unroll
      for (int rr = 0; rr < 4; ++rr){
        int n = m0 + wm*64 + i*16 + rq*4 + rr;
        #pragma unroll
        for (int j = 0; j < 4; ++j){
          int l = n0 + wn*64 + j*16 + col;
          if (l < NL)
            Gt[((size_t)b*ND + n)*800 + q*NL + l] = f2bf(acc[i][j][rr]);
        }
      }
    }
  }
}

// =========== K3: FUSED softmax + V-GEMM per (b, 32-t tile) =====================
// Phase 2 K-loop is BARRIER-FREE: A (w-tile) from LDS, B (Gt rows) loaded
// directly to registers (16B contiguous per lane) -> compiler-pipelined
// MFMA<->VMEM, no vmcnt(0) drains. LDS 51.5 KB -> 3 blocks/CU.
#define AP 808
__global__ __launch_bounds__(256) void k_wv_fused(
    const float4* __restrict__ base,
    const int* __restrict__ fl_ws,
    const float* __restrict__ Mw, const float* __restrict__ Mc,
    const ushort_t* __restrict__ Gt,    // [16][256][800] bf16
    const float* __restrict__ Lc,       // [8][256]
    const float* __restrict__ lbc,      // [256]
    const float* __restrict__ lbw,      // [256]
    float* __restrict__ wout,
    ushort_t* __restrict__ whc)         // [16000][256] bf16
{
  __shared__ ushort_t As[32*AP];   // 50.5 KB w-tile [t_local][k=q*200+l]
  __shared__ float    wcs[32][8];  // 1 KB per-t wc
  int b = blockIdx.y;
  int m0 = blockIdx.x * 32;        // t tile (32 tiles cover 0..1023)
  int tid = threadIdx.x, lane = tid & 63, wave = tid >> 6;
  int col = lane & 15, kg4 = lane >> 4;
  int fl = fl_ws[b];

  // ---------------- phase 1: softmax for 8 t's per wave ----------------
  for (int s = 0; s < 8; ++s){
    int tl = wave*8 + s;
    int t = m0 + tl;
    if (t >= fl){                       // masked or beyond NT
      for (int k = lane; k < 800; k += 64) As[tl*AP + k] = 0;
      if (lane < 8) wcs[tl][lane] = 0.f;
      if (t < NT){
        #pragma unroll
        for (int q = 0; q < 4; ++q)
          #pragma unroll
          for (int c = 0; c < 4; ++c){
            int l = c*64 + lane;
            if (l < NL) wout[(((size_t)(b*4 + q))*NT + t)*NL + l] = 0.f;
          }
      }
      continue;
    }
    float t1 = (float)(t + 1);
    float tqw[4], tqc[2];
    #pragma unroll
    for (int q = 0; q < 4; ++q) tqw[q] = t1 * Mw[q];
    #pragma unroll
    for (int p = 0; p < 2; ++p) tqc[p] = t1 * Mc[p];
    float z[4][4], cv[4][2], msk[4];
    float m[4] = {-INFINITY, -INFINITY, -INFINITY, -INFINITY};
    #pragma unroll
    for (int c = 0; c < 4; ++c){
      int l = c*64 + lane;
      float4 b0 = base[((size_t)(b*256 + l))*2 + 0];
      float4 b1 = base[((size_t)(b*256 + l))*2 + 1];
      float pm = b1.z;
      msk[c] = pm;
      float zz[4] = { b0.x + tqw[0], b0.y + tqw[1], b0.z + tqw[2], b0.w + tqw[3] };
      #pragma unroll
      for (int q = 0; q < 4; ++q){
        float sv = silu_f(zz[q]);
        z[c][q] = (pm > 0.f) ? sv : -INFINITY;
        m[q] = fmaxf(m[q], z[c][q]);
      }
      cv[c][0] = silu_f(b1.x + tqc[0]);
      cv[c][1] = silu_f(b1.y + tqc[1]);
    }
    #pragma unroll
    for (int q = 0; q < 4; ++q){
      float v = m[q];
      #pragma unroll
      for (int off = 32; off; off >>= 1) v = fmaxf(v, __shfl_xor(v, off));
      m[q] = v;
    }
    float s4[4] = {0,0,0,0};
    #pragma unroll
    for (int c = 0; c < 4; ++c){
      #pragma unroll
      for (int q = 0; q < 4; ++q){
        float e = (msk[c] > 0.f) ? __expf(z[c][q] - m[q]) : 0.f;
        z[c][q] = e;
        s4[q] += e;
      }
    }
    #pragma unroll
    for (int q = 0; q < 4; ++q){
      float v = s4[q];
      #pragma unroll
      for (int off = 32; off; off >>= 1) v += __shfl_xor(v, off);
      s4[q] = 1.f / v;
    }
    float wc[8] = {0,0,0,0,0,0,0,0};
    #pragma unroll
    for (int c = 0; c < 4; ++c){
      int l = c*64 + lane;
      bool lv = l < NL;
      #pragma unroll
      for (int q = 0; q < 4; ++q){
        float wq = z[c][q] * s4[q];
        if (lv){
          wout[(((size_t)(b*4 + q))*NT + t)*NL + l] = wq;
          As[tl*AP + q*NL + l] = f2bf(wq);
        }
        wc[q*2 + 0] += wq * cv[c][0];
        wc[q*2 + 1] += wq * cv[c][1];
      }
    }
    #pragma unroll
    for (int u = 0; u < 8; ++u){
      float v = wc[u];
      #pragma unroll
      for (int off = 32; off; off >>= 1) v += __shfl_xor(v, off);
      wc[u] = v;
    }
    if (lane == 0){
      #pragma unroll
      for (int u = 0; u < 8; ++u) wcs[tl][u] = wc[u];
    }
  }
  __syncthreads();

  // ---------------- phase 2: MFMA over K=800, barrier-free ----------------
  f32x4 acc[2][4] = {};
  const ushort_t* Gb = Gt + (size_t)b*ND*800;
  for (int kt = 0; kt < 25; ++kt){
    int k0 = kt*32;
    bf16x8 afr[2], bfr[4];
    #pragma unroll
    for (int i = 0; i < 2; ++i)
      afr[i] = *(const bf16x8*)(&As[(i*16 + col)*AP + k0 + kg4*8]);
    #pragma unroll
    for (int j = 0; j < 4; ++j)
      bfr[j] = *(const bf16x8*)(Gb + ((size_t)(wave*64 + j*16 + col))*800 + k0 + kg4*8);
    #pragma unroll
    for (int i = 0; i < 2; ++i)
      #pragma unroll
      for (int j = 0; j < 4; ++j)
        acc[i][j] = __builtin_amdgcn_mfma_f32_16x16x32_bf16(afr[i], bfr[j], acc[i][j], 0, 0, 0);
  }

  // ---- epilogue: whc[t][n] = fm*(vh + lbw + (lbc + wc.Lc)) -> global ----
  int rq = lane >> 4;
  float lcn[4][8], lbn[4], lbwn[4];
  #pragma unroll
  for (int j = 0; j < 4; ++j){
    int n = wave*64 + j*16 + col;
    lbn[j] = lbc[n]; lbwn[j] = lbw[n];
    #pragma unroll
    for (int u = 0; u < 8; ++u) lcn[j][u] = Lc[u*ND + n];
  }
  #pragma unroll
  for (int i = 0; i < 2; ++i){
    #pragma unroll
    for (int r = 0; r < 4; ++r){
      int tl = i*16 + rq*4 + r;
      int t = m0 + tl;
      if (t >= NT) continue;
      float f = (t < fl) ? 1.f : 0.f;
      #pragma unroll
      for (int j = 0; j < 4; ++j){
        float vcv = lbn[j]
          + wcs[tl][0]*lcn[j][0] + wcs[tl][1]*lcn[j][1]
          + wcs[tl][2]*lcn[j][2] + wcs[tl][3]*lcn[j][3]
          + wcs[tl][4]*lcn[j][4] + wcs[tl][5]*lcn[j][5]
          + wcs[tl][6]*lcn[j][6] + wcs[tl][7]*lcn[j][7];
        int n = wave*64 + j*16 + col;
        whc[((size_t)b*NT + t)*ND + n] = f2bf(f * (acc[i][j][r] + lbwn[j] + vcv));
      }
    }
  }
}

// ------- K4: MFMA out = WoT x whc^T — zero LDS, zero barriers ------------------
__global__ __launch_bounds__(256) void k_gemmO_mfma(
    const ushort_t* __restrict__ whc,   // [16000][256] bf16
    const ushort_t* __restrict__ WoT,   // [512][256] bf16
    const float* __restrict__ bo,       // [512]
    float* __restrict__ o_mean, float* __restrict__ o_lstd)
{
  int m0 = blockIdx.y * 128;            // s (4 tiles over 512)
  int n0 = blockIdx.x * 128;            // bt (125 tiles over 16000)
  int tid = threadIdx.x, lane = tid & 63, wave = tid >> 6;
  int wm = wave >> 1, wn = wave & 1;
  int col = lane & 15, kg4 = lane >> 4;

  f32x4 acc[4][4] = {};

  for (int kt = 0; kt < 8; ++kt){
    int k0 = kt*32;
    bf16x8 afr[4], bfr[4];
    #pragma unroll
    for (int i = 0; i < 4; ++i)
      afr[i] = *(const bf16x8*)(WoT + ((size_t)(m0 + wm*64 + i*16 + col))*ND + k0 + kg4*8);
    #pragma unroll
    for (int j = 0; j < 4; ++j)
      bfr[j] = *(const bf16x8*)(whc + ((size_t)(n0 + wn*64 + j*16 + col))*ND + k0 + kg4*8);
    #pragma unroll
    for (int i = 0; i < 4; ++i)
      #pragma unroll
      for (int j = 0; j < 4; ++j)
        acc[i][j] = __builtin_amdgcn_mfma_f32_16x16x32_bf16(afr[i], bfr[j], acc[i][j], 0, 0, 0);
  }

  int rq = lane >> 4;
  #pragma unroll
  for (int i = 0; i < 4; ++i){
    #pragma unroll
    for (int r = 0; r < 4; ++r){
      int s = m0 + wm*64 + i*16 + rq*4 + r;
      float bov = bo[s];
      #pragma unroll
      for (int j = 0; j < 4; ++j){
        int bt = n0 + wn*64 + j*16 + col;
        int b = bt / NT, t = bt - b*NT;
        float v = acc[i][j][r] + bov;
        if (s < ND) o_mean[((size_t)b*ND + s)*NT + t] = v;
        else        o_lstd[((size_t)b*ND + (s - ND))*NT + t] = v;
      }
    }
  }
}

extern "C" void kernel_launch(void* const* d_in, const int* in_sizes, int n_in,
                              void* d_out, int out_size, void* d_ws, size_t ws_size,
                              hipStream_t stream)
{
  const float* dur = (const float*)d_in[0];
  const float* ph  = (const float*)d_in[1];
  // d_in[2] phoneme_mask: unused (pm == durations > 0)
  const float* Wpw = (const float*)d_in[3];
  const float* bpw = (const float*)d_in[4];
  const float* Cw  = (const float*)d_in[5];
  const float* cbw = (const float*)d_in[6];
  const float* Mw  = (const float*)d_in[7];
  const float* mbw = (const float*)d_in[8];
  const float* Lw  = (const float*)d_in[9];
  const float* lbw = (const float*)d_in[10];
  const float* Wpc = (const float*)d_in[11];
  const float* bpc = (const float*)d_in[12];
  const float* Cc  = (const float*)d_in[13];
  const float* cbc = (const float*)d_in[14];
  const float* Mc  = (const float*)d_in[15];
  const float* mbc = (const float*)d_in[16];
  const float* Lc  = (const float*)d_in[17];
  const float* lbc = (const float*)d_in[18];
  const float* Wo  = (const float*)d_in[19];
  const float* bo  = (const float*)d_in[20];

  float* out    = (float*)d_out;
  float* o_mean = out;
  float* o_lstd = out + (size_t)NB*ND*NT;
  float* o_fm   = o_lstd + (size_t)NB*ND*NT;
  float* o_fl   = o_fm + NB*NT;
  float* o_w    = o_fl + NB;

  float* ws   = (float*)d_ws;
  float* phT  = ws + OFF_PHT;
  float* sk   = ws + OFF_SK;
  float* Ew   = ws + OFF_EW;
  float* Ec   = ws + OFF_EC;
  float* bw2  = ws + OFF_BW2;
  float* bc2  = ws + OFF_BC2;
  int*   fl   = (int*)(ws + OFF_FL);
  ushort_t* Gt   = (ushort_t*)(ws + OFF_GT);
  ushort_t* whc  = (ushort_t*)(ws + OFF_WHC);
  ushort_t* WoT  = (ushort_t*)(ws + OFF_WOT);
  float4*   base = (float4*)(ws + OFF_BASE);
  ushort_t* phTb = (ushort_t*)(ws + OFF_PHTB);
  ushort_t* LwT  = (ushort_t*)(ws + OFF_LWT);

  k_stage1<<<2624, 256, 0, stream>>>(dur, ph, Wpw, Cw, bpw, Wpc, Cc, bpc, Wo, Lw,
                                     sk, fl, o_fm, o_fl, Ew, Ec, bw2, bc2,
                                     WoT, LwT, phT, phTb);
  k_stage2<<<512, 256, 0, stream>>>(phT, dur, sk, Ew, Ec, bw2, bc2, cbw, cbc,
                                    Mw, mbw, Mc, mbc, base, LwT, phTb, Gt);
  {
    dim3 g(32, NB);
    k_wv_fused<<<g, 256, 0, stream>>>(base, fl, Mw, Mc, Gt, Lc, lbc, lbw,
                                      o_w, whc);
  }
  {
    dim3 g(125, 4);
    k_gemmO_mfma<<<g, 256, 0, stream>>>(whc, WoT, bo, o_mean, o_lstd);
  }
}